// Round 1
// baseline (2884.759 us; speedup 1.0000x reference)
//
#include <hip/hip_runtime.h>

#define B_ 8
#define C_ 3
#define R_ 8
#define H_ 512
#define W_ 512
#define HW_ (H_*W_)
#define S_ 1024
#define CB_ 25
#define TB_ 10

// output offsets (floats)
#define O_AREA 0
#define N_AREA (B_*S_)                  // 8192
#define O_BBOX (O_AREA + N_AREA)        // 8192
#define N_BBOX (B_*S_*4)                // 32768
#define O_COLOR (O_BBOX + N_BBOX)       // 40960
#define N_COLOR (B_*S_*C_*CB_)          // 614400
#define O_TEX (O_COLOR + N_COLOR)       // 655360
#define N_TEX (B_*S_*C_*R_*TB_)        // 1966080
#define O_GRADS (O_TEX + N_TEX)         // 2621440
#define N_GRADS (B_*C_*2*HW_)           // 12582912

// ---------------- init: zero accumulators, bbox mins to 512 ----------------
__global__ void k_init(float* __restrict__ out) {
  const int total = O_GRADS;  // 2621440 floats to init
  for (int i = blockIdx.x * blockDim.x + threadIdx.x; i < total;
       i += gridDim.x * blockDim.x) {
    float v = 0.0f;
    if (i >= O_BBOX && i < O_COLOR) {
      if (((i - O_BBOX) & 3) < 2) v = 512.0f;  // xmin=W, ymin=H
    }
    out[i] = v;
  }
}

// ---------------- area + bbox, LDS-privatized per block ----------------
__global__ __launch_bounds__(256) void k_area_bbox(const int* __restrict__ lab,
                                                   float* __restrict__ out) {
  __shared__ int s_cnt[S_];
  __shared__ int s_xmin[S_];
  __shared__ int s_ymin[S_];
  __shared__ int s_xmax[S_];
  __shared__ int s_ymax[S_];
  const int b = blockIdx.y;
  for (int i = threadIdx.x; i < S_; i += blockDim.x) {
    s_cnt[i] = 0; s_xmin[i] = W_; s_ymin[i] = H_; s_xmax[i] = 0; s_ymax[i] = 0;
  }
  __syncthreads();
  const int chunk = HW_ / gridDim.x;
  const int base = blockIdx.x * chunk;
  const int* lb = lab + b * HW_;
  for (int p = base + threadIdx.x; p < base + chunk; p += blockDim.x) {
    int l = lb[p];
    int x = p & (W_ - 1);
    int y = p >> 9;
    atomicAdd(&s_cnt[l], 1);
    atomicMin(&s_xmin[l], x);
    atomicMin(&s_ymin[l], y);
    atomicMax(&s_xmax[l], x);
    atomicMax(&s_ymax[l], y);
  }
  __syncthreads();
  for (int i = threadIdx.x; i < S_; i += blockDim.x) {
    int c = s_cnt[i];
    if (c > 0) {
      atomicAdd(&out[O_AREA + b * S_ + i], (float)c);
      float* bb = out + O_BBOX + (size_t)(b * S_ + i) * 4;
      // positive floats: int compare == float compare
      atomicMin((int*)(bb + 0), __float_as_int((float)s_xmin[i]));
      atomicMin((int*)(bb + 1), __float_as_int((float)s_ymin[i]));
      atomicMax((int*)(bb + 2), __float_as_int((float)s_xmax[i]));
      atomicMax((int*)(bb + 3), __float_as_int((float)s_ymax[i]));
    }
  }
}

// ---------------- color histogram: [B,S,C,CB] float atomics ----------------
__global__ void k_color(const int* __restrict__ bins, const int* __restrict__ lab,
                        float* __restrict__ out) {
  const int tot4 = (B_ * C_ * HW_) / 4;  // 1572864
  for (int t = blockIdx.x * blockDim.x + threadIdx.x; t < tot4;
       t += gridDim.x * blockDim.x) {
    const int i = t * 4;
    const int pix = i & (HW_ - 1);
    const int bc = i >> 18;          // b*C + c
    const int b = bc / C_;
    const int c = bc - b * C_;
    const int4 bn = ((const int4*)bins)[t];
    const int4 lv = *(const int4*)(lab + b * HW_ + pix);
    const int segbase = O_COLOR + (b * S_) * (C_ * CB_) + c * CB_;
    atomicAdd(&out[segbase + lv.x * (C_ * CB_) + bn.x], 1.0f);
    atomicAdd(&out[segbase + lv.y * (C_ * CB_) + bn.y], 1.0f);
    atomicAdd(&out[segbase + lv.z * (C_ * CB_) + bn.z], 1.0f);
    atomicAdd(&out[segbase + lv.w * (C_ * CB_) + bn.w], 1.0f);
  }
}

// ---------------- texture histogram: [B,S,C*R,TB] float atomics ----------------
__global__ void k_tex(const int* __restrict__ bins, const int* __restrict__ lab,
                      float* __restrict__ out) {
  const int tot4 = (B_ * C_ * R_ * HW_) / 4;  // 12582912
  for (int t = blockIdx.x * blockDim.x + threadIdx.x; t < tot4;
       t += gridDim.x * blockDim.x) {
    const int i = t * 4;
    const int pix = i & (HW_ - 1);
    const int bcr = i >> 18;          // (b*C + c)*R + r
    const int b = bcr / (C_ * R_);
    const int cr = bcr - b * (C_ * R_);   // c*R + r
    const int4 bn = ((const int4*)bins)[t];
    const int4 lv = *(const int4*)(lab + b * HW_ + pix);
    const int segbase = O_TEX + (b * S_) * (C_ * R_ * TB_) + cr * TB_;
    atomicAdd(&out[segbase + lv.x * (C_ * R_ * TB_) + bn.x], 1.0f);
    atomicAdd(&out[segbase + lv.y * (C_ * R_ * TB_) + bn.y], 1.0f);
    atomicAdd(&out[segbase + lv.z * (C_ * R_ * TB_) + bn.z], 1.0f);
    atomicAdd(&out[segbase + lv.w * (C_ * R_ * TB_) + bn.w], 1.0f);
  }
}

// ---------------- Scharr gradients (cross-correlation, SAME zero pad) ----------------
__global__ void k_conv(const float* __restrict__ img, float* __restrict__ out) {
  const int tot = B_ * C_ * HW_;
  for (int i = blockIdx.x * blockDim.x + threadIdx.x; i < tot;
       i += gridDim.x * blockDim.x) {
    const int pix = i & (HW_ - 1);
    const int bc = i >> 18;
    const int x = pix & (W_ - 1);
    const int y = pix >> 9;
    const float* im = img + (size_t)bc * HW_;
    const bool xm = x > 0, xp = x < W_ - 1, ym = y > 0, yp = y < H_ - 1;
    const float i00 = (ym && xm) ? im[pix - W_ - 1] : 0.f;
    const float i01 = ym ? im[pix - W_] : 0.f;
    const float i02 = (ym && xp) ? im[pix - W_ + 1] : 0.f;
    const float i10 = xm ? im[pix - 1] : 0.f;
    const float i12 = xp ? im[pix + 1] : 0.f;
    const float i20 = (yp && xm) ? im[pix + W_ - 1] : 0.f;
    const float i21 = yp ? im[pix + W_] : 0.f;
    const float i22 = (yp && xp) ? im[pix + W_ + 1] : 0.f;
    const float gx = 3.f * (i02 - i00) + 10.f * (i12 - i10) + 3.f * (i22 - i20);
    const float gy = 3.f * (i20 - i00) + 10.f * (i21 - i01) + 3.f * (i22 - i02);
    out[O_GRADS + (size_t)(bc * 2 + 0) * HW_ + pix] = gx;
    out[O_GRADS + (size_t)(bc * 2 + 1) * HW_ + pix] = gy;
  }
}

// ---------------- bbox finalize: w = xmax - xmin, h = ymax - ymin ----------------
__global__ void k_bbox_fin(float* __restrict__ out) {
  const int i = blockIdx.x * blockDim.x + threadIdx.x;
  if (i < B_ * S_) {
    float* bb = out + O_BBOX + (size_t)i * 4;
    bb[2] = bb[2] - bb[0];
    bb[3] = bb[3] - bb[1];
  }
}

// ---------------- normalize histograms by area ----------------
__global__ void k_norm(float* __restrict__ out) {
  const int tot = N_COLOR + N_TEX;
  for (int i = blockIdx.x * blockDim.x + threadIdx.x; i < tot;
       i += gridDim.x * blockDim.x) {
    if (i < N_COLOR) {
      const int bs = i / (C_ * CB_);
      const float a = out[O_AREA + bs];
      out[O_COLOR + i] = out[O_COLOR + i] / (a * 3.0f + 1e-12f);
    } else {
      const int j = i - N_COLOR;
      const int bs = j / (C_ * R_ * TB_);
      const float a = out[O_AREA + bs];
      out[O_TEX + j] = out[O_TEX + j] / (a * 24.0f + 1e-12f);
    }
  }
}

extern "C" void kernel_launch(void* const* d_in, const int* in_sizes, int n_in,
                              void* d_out, int out_size, void* d_ws, size_t ws_size,
                              hipStream_t stream) {
  const float* img = (const float*)d_in[0];
  const int* imgs_bins = (const int*)d_in[1];
  const int* grads_bins = (const int*)d_in[2];
  const int* reg_lab = (const int*)d_in[3];
  float* out = (float*)d_out;

  hipLaunchKernelGGL(k_init, dim3(2048), dim3(256), 0, stream, out);
  hipLaunchKernelGGL(k_area_bbox, dim3(16, B_), dim3(256), 0, stream, reg_lab, out);
  hipLaunchKernelGGL(k_color, dim3(6144), dim3(256), 0, stream, imgs_bins, reg_lab, out);
  hipLaunchKernelGGL(k_tex, dim3(8192), dim3(256), 0, stream, grads_bins, reg_lab, out);
  hipLaunchKernelGGL(k_conv, dim3(8192), dim3(256), 0, stream, img, out);
  hipLaunchKernelGGL(k_bbox_fin, dim3(32), dim3(256), 0, stream, out);
  hipLaunchKernelGGL(k_norm, dim3(8192), dim3(256), 0, stream, out);
}

// Round 2
// 109.661 us; speedup vs baseline: 26.3061x; 26.3061x over previous
//
#include <hip/hip_runtime.h>

#define B_ 8
#define C_ 3
#define R_ 8
#define H_ 512
#define W_ 512
#define HW_ (H_*W_)
#define S_ 1024
#define CB_ 25
#define TB_ 10

// output offsets (floats)
#define O_AREA 0
#define O_BBOX 8192
#define O_COLOR 40960
#define O_TEX 655360
#define O_GRADS 2621440
#define N_GRADS (B_*C_*2*HW_)

// chunking
#define TEXC 4            // chunks per (b,c,r) texture plane -> 768 blocks
#define COLC 4            // chunks per (b,c) color plane     -> 96 blocks
#define ABC 16            // chunks per image for area/bbox   -> 128 blocks

// scratch inside the (later-overwritten) grads output region
#define SCR_TEX ((size_t)O_GRADS)                                   // 768*10240 floats
#define SCR_COL (SCR_TEX + (size_t)(B_*C_*R_*TEXC)*(S_*TB_))        // 96*25600 floats
#define SCR_AB  (SCR_COL + (size_t)(B_*C_*COLC)*(S_*CB_))           // 128*5*1024 ints

// ---------------- area + bbox partials (LDS) -> scratch ----------------
__global__ __launch_bounds__(256) void k_ab_part(const int* __restrict__ lab,
                                                 float* __restrict__ out) {
  __shared__ int s[5*S_];   // cnt, xmin, ymin, xmax, ymax
  const int b = blockIdx.y;
  const int blk = blockIdx.x;  // 0..ABC-1
  for (int i = threadIdx.x; i < S_; i += 256) {
    s[i] = 0; s[S_+i] = W_; s[2*S_+i] = H_; s[3*S_+i] = 0; s[4*S_+i] = 0;
  }
  __syncthreads();
  const int chunk = HW_/ABC;             // 16384 pixels
  const int base = blk*chunk;
  const int4* lp = (const int4*)(lab + b*HW_ + base);
  const int n4 = chunk/4;
  for (int t = threadIdx.x; t < n4; t += 256) {
    int4 lv = lp[t];
    int p = base + t*4;
    int y = p >> 9;
    int x = p & (W_-1);    // x..x+3 stay in row (W=512, 4-aligned)
    atomicAdd(&s[lv.x],1); atomicMin(&s[S_+lv.x],x);   atomicMin(&s[2*S_+lv.x],y);
    atomicMax(&s[3*S_+lv.x],x);   atomicMax(&s[4*S_+lv.x],y);
    atomicAdd(&s[lv.y],1); atomicMin(&s[S_+lv.y],x+1); atomicMin(&s[2*S_+lv.y],y);
    atomicMax(&s[3*S_+lv.y],x+1); atomicMax(&s[4*S_+lv.y],y);
    atomicAdd(&s[lv.z],1); atomicMin(&s[S_+lv.z],x+2); atomicMin(&s[2*S_+lv.z],y);
    atomicMax(&s[3*S_+lv.z],x+2); atomicMax(&s[4*S_+lv.z],y);
    atomicAdd(&s[lv.w],1); atomicMin(&s[S_+lv.w],x+3); atomicMin(&s[2*S_+lv.w],y);
    atomicMax(&s[3*S_+lv.w],x+3); atomicMax(&s[4*S_+lv.w],y);
  }
  __syncthreads();
  int* scr = (int*)(out + SCR_AB) + (size_t)(b*ABC + blk)*5*S_;
  for (int i = threadIdx.x; i < 5*S_; i += 256) scr[i] = s[i];
}

// ---------------- area + bbox final: exclusive-owner plain stores ----------------
__global__ void k_ab_reduce(float* __restrict__ out) {
  const int idx = blockIdx.x*blockDim.x + threadIdx.x;  // B*S = 8192
  if (idx >= B_*S_) return;
  const int b = idx >> 10, l = idx & (S_-1);
  const int* scr = (const int*)(out + SCR_AB);
  int cnt = 0, xmn = W_, ymn = H_, xmx = 0, ymx = 0;
  for (int k = 0; k < ABC; ++k) {
    const int* p = scr + (size_t)(b*ABC + k)*5*S_;
    cnt += p[l];
    xmn = min(xmn, p[S_+l]);   ymn = min(ymn, p[2*S_+l]);
    xmx = max(xmx, p[3*S_+l]); ymx = max(ymx, p[4*S_+l]);
  }
  out[O_AREA + idx] = (float)cnt;
  float* bb = out + O_BBOX + (size_t)idx*4;
  bb[0] = (float)xmn; bb[1] = (float)ymn;
  bb[2] = (float)(xmx - xmn); bb[3] = (float)(ymx - ymn);
}

// ---------------- texture hist partials: LDS (S*TB ints = 40KB) ----------------
__global__ __launch_bounds__(1024) void k_tex_part(const int* __restrict__ bins,
                                                   const int* __restrict__ lab,
                                                   float* __restrict__ out) {
  __shared__ int h[S_*TB_];
  const int blk = blockIdx.x;          // plane*TEXC + chunk, 768 total
  const int plane = blk >> 2;          // b*24 + c*8 + r
  const int chunk = blk & 3;
  for (int i = threadIdx.x; i < S_*TB_; i += 1024) h[i] = 0;
  __syncthreads();
  const int b = plane / (C_*R_);
  const int n4 = HW_/TEXC/4;           // 16384 int4 per chunk
  const int4* bp = (const int4*)(bins + (size_t)plane*HW_) + chunk*n4;
  const int4* lp = (const int4*)(lab + (size_t)b*HW_) + chunk*n4;
  for (int t = threadIdx.x; t < n4; t += 1024) {
    int4 bn = bp[t];
    int4 lv = lp[t];
    atomicAdd(&h[lv.x*TB_ + bn.x], 1);
    atomicAdd(&h[lv.y*TB_ + bn.y], 1);
    atomicAdd(&h[lv.z*TB_ + bn.z], 1);
    atomicAdd(&h[lv.w*TB_ + bn.w], 1);
  }
  __syncthreads();
  float* scr = out + SCR_TEX + (size_t)blk*(S_*TB_);
  for (int i = threadIdx.x; i < S_*TB_; i += 1024) scr[i] = (float)h[i];
}

// ---------------- texture reduce + normalize: exclusive stores ----------------
__global__ void k_tex_reduce(float* __restrict__ out) {
  const int idx = blockIdx.x*blockDim.x + threadIdx.x;  // 192*10240 = 1,966,080
  if (idx >= B_*C_*R_*S_*TB_) return;
  const int plane = idx / (S_*TB_);
  const int j = idx - plane*(S_*TB_);
  const float* scr = out + SCR_TEX + (size_t)plane*TEXC*(S_*TB_);
  float s = scr[j] + scr[j + S_*TB_] + scr[j + 2*S_*TB_] + scr[j + 3*S_*TB_];
  const int b = plane / (C_*R_), cr = plane - b*(C_*R_);
  const int l = j / TB_, t = j - l*TB_;
  const float a = out[O_AREA + b*S_ + l];
  out[O_TEX + (size_t)b*(S_*C_*R_*TB_) + l*(C_*R_*TB_) + cr*TB_ + t]
      = s / (a * 24.0f + 1e-12f);
}

// ---------------- color hist partials: LDS packed 2x u16 (50KB) ----------------
__global__ __launch_bounds__(1024) void k_col_part(const int* __restrict__ bins,
                                                   const int* __restrict__ lab,
                                                   float* __restrict__ out) {
  __shared__ unsigned h[(S_*CB_)/2];   // 12800 words, 2 u16 counts each
  const int blk = blockIdx.x;          // plane*COLC + chunk, 96 total
  const int plane = blk >> 2;          // b*3 + c
  const int chunk = blk & 3;
  for (int i = threadIdx.x; i < (S_*CB_)/2; i += 1024) h[i] = 0;
  __syncthreads();
  const int b = plane / C_;
  const int n4 = HW_/COLC/4;           // 16384
  const int4* bp = (const int4*)(bins + (size_t)plane*HW_) + chunk*n4;
  const int4* lp = (const int4*)(lab + (size_t)b*HW_) + chunk*n4;
  for (int t = threadIdx.x; t < n4; t += 1024) {
    int4 bn = bp[t];
    int4 lv = lp[t];
    int j0 = lv.x*CB_ + bn.x;
    int j1 = lv.y*CB_ + bn.y;
    int j2 = lv.z*CB_ + bn.z;
    int j3 = lv.w*CB_ + bn.w;
    atomicAdd(&h[j0>>1], 1u << ((j0&1)<<4));
    atomicAdd(&h[j1>>1], 1u << ((j1&1)<<4));
    atomicAdd(&h[j2>>1], 1u << ((j2&1)<<4));
    atomicAdd(&h[j3>>1], 1u << ((j3&1)<<4));
  }
  __syncthreads();
  float* scr = out + SCR_COL + (size_t)blk*(S_*CB_);
  for (int j = threadIdx.x; j < S_*CB_; j += 1024) {
    unsigned w = h[j>>1];
    scr[j] = (float)((w >> ((j&1)<<4)) & 0xFFFFu);
  }
}

// ---------------- color reduce + normalize ----------------
__global__ void k_col_reduce(float* __restrict__ out) {
  const int idx = blockIdx.x*blockDim.x + threadIdx.x;  // 24*25600 = 614,400
  if (idx >= B_*C_*S_*CB_) return;
  const int plane = idx / (S_*CB_);
  const int j = idx - plane*(S_*CB_);
  const float* scr = out + SCR_COL + (size_t)plane*COLC*(S_*CB_);
  float s = scr[j] + scr[j + S_*CB_] + scr[j + 2*S_*CB_] + scr[j + 3*S_*CB_];
  const int b = plane / C_, c = plane - b*C_;
  const int l = j / CB_, ci = j - l*CB_;
  const float a = out[O_AREA + b*S_ + l];
  out[O_COLOR + (size_t)b*(S_*C_*CB_) + l*(C_*CB_) + c*CB_ + ci]
      = s / (a * 3.0f + 1e-12f);
}

// ---------------- Scharr gradients (cross-correlation, SAME zero pad) ----------------
__global__ void k_conv(const float* __restrict__ img, float* __restrict__ out) {
  const int tot = B_*C_*HW_;
  for (int i = blockIdx.x*blockDim.x + threadIdx.x; i < tot;
       i += gridDim.x*blockDim.x) {
    const int pix = i & (HW_-1);
    const int bc = i >> 18;
    const int x = pix & (W_-1);
    const int y = pix >> 9;
    const float* im = img + (size_t)bc*HW_;
    const bool xm = x > 0, xp = x < W_-1, ym = y > 0, yp = y < H_-1;
    const float i00 = (ym && xm) ? im[pix - W_ - 1] : 0.f;
    const float i01 = ym ? im[pix - W_] : 0.f;
    const float i02 = (ym && xp) ? im[pix - W_ + 1] : 0.f;
    const float i10 = xm ? im[pix - 1] : 0.f;
    const float i12 = xp ? im[pix + 1] : 0.f;
    const float i20 = (yp && xm) ? im[pix + W_ - 1] : 0.f;
    const float i21 = yp ? im[pix + W_] : 0.f;
    const float i22 = (yp && xp) ? im[pix + W_ + 1] : 0.f;
    const float gx = 3.f*(i02 - i00) + 10.f*(i12 - i10) + 3.f*(i22 - i20);
    const float gy = 3.f*(i20 - i00) + 10.f*(i21 - i01) + 3.f*(i22 - i02);
    out[O_GRADS + (size_t)(bc*2 + 0)*HW_ + pix] = gx;
    out[O_GRADS + (size_t)(bc*2 + 1)*HW_ + pix] = gy;
  }
}

extern "C" void kernel_launch(void* const* d_in, const int* in_sizes, int n_in,
                              void* d_out, int out_size, void* d_ws, size_t ws_size,
                              hipStream_t stream) {
  const float* img = (const float*)d_in[0];
  const int* imgs_bins = (const int*)d_in[1];
  const int* grads_bins = (const int*)d_in[2];
  const int* reg_lab = (const int*)d_in[3];
  float* out = (float*)d_out;

  hipLaunchKernelGGL(k_ab_part, dim3(ABC, B_), dim3(256), 0, stream, reg_lab, out);
  hipLaunchKernelGGL(k_ab_reduce, dim3(32), dim3(256), 0, stream, out);
  hipLaunchKernelGGL(k_tex_part, dim3(B_*C_*R_*TEXC), dim3(1024), 0, stream,
                     grads_bins, reg_lab, out);
  hipLaunchKernelGGL(k_col_part, dim3(B_*C_*COLC), dim3(1024), 0, stream,
                     imgs_bins, reg_lab, out);
  hipLaunchKernelGGL(k_tex_reduce, dim3((B_*C_*R_*S_*TB_)/256), dim3(256), 0, stream, out);
  hipLaunchKernelGGL(k_col_reduce, dim3((B_*C_*S_*CB_)/256), dim3(256), 0, stream, out);
  hipLaunchKernelGGL(k_conv, dim3(8192), dim3(256), 0, stream, img, out);
}

// Round 3
// 78.119 us; speedup vs baseline: 36.9275x; 1.4038x over previous
//
#include <hip/hip_runtime.h>

#define B_ 8
#define C_ 3
#define R_ 8
#define H_ 512
#define W_ 512
#define HW_ (H_*W_)
#define S_ 1024
#define CB_ 25
#define TB_ 10

// output offsets (floats)
#define O_AREA 0
#define O_BBOX 8192
#define O_COLOR 40960
#define O_TEX 655360
#define O_GRADS 2621440

// block roles
#define NBBOX 8
#define NTEX (B_*C_*R_)        // 192
#define NCOL (B_*C_)           // 24
#define NHIST (NBBOX + NTEX + NCOL)   // 224
#define NCONV 1024
#define NGRID (NHIST + NCONV)

__global__ __launch_bounds__(1024) void k_fused(
    const float* __restrict__ img,
    const int* __restrict__ imgs_bins,
    const int* __restrict__ grads_bins,
    const int* __restrict__ lab,
    float* __restrict__ out) {
  __shared__ unsigned smem[12800];   // 51.2 KB union
  const int bid = blockIdx.x;
  const int tid = threadIdx.x;

  if (bid < NBBOX) {
    // ---------- bbox for image b: LDS min/max, exclusive final write ----------
    const int b = bid;
    int* mn = (int*)smem;   // xmin[S], ymin[S], xmax[S], ymax[S] = 16 KB
    for (int i = tid; i < S_; i += 1024) {
      mn[i] = W_; mn[S_ + i] = H_; mn[2*S_ + i] = 0; mn[3*S_ + i] = 0;
    }
    __syncthreads();
    const int4* lp = (const int4*)(lab + (size_t)b * HW_);
    for (int t = tid; t < HW_/4; t += 1024) {
      const int4 lv = lp[t];
      const int p = t * 4;
      const int y = p >> 9;
      const int x = p & (W_ - 1);   // W=512, 4-aligned: x..x+3 same row
      atomicMin(&mn[lv.x], x);       atomicMin(&mn[S_ + lv.x], y);
      atomicMax(&mn[2*S_ + lv.x], x);   atomicMax(&mn[3*S_ + lv.x], y);
      atomicMin(&mn[lv.y], x + 1);   atomicMin(&mn[S_ + lv.y], y);
      atomicMax(&mn[2*S_ + lv.y], x + 1); atomicMax(&mn[3*S_ + lv.y], y);
      atomicMin(&mn[lv.z], x + 2);   atomicMin(&mn[S_ + lv.z], y);
      atomicMax(&mn[2*S_ + lv.z], x + 2); atomicMax(&mn[3*S_ + lv.z], y);
      atomicMin(&mn[lv.w], x + 3);   atomicMin(&mn[S_ + lv.w], y);
      atomicMax(&mn[2*S_ + lv.w], x + 3); atomicMax(&mn[3*S_ + lv.w], y);
    }
    __syncthreads();
    // thread l owns label l (blockDim == S)
    {
      const int xmn = mn[tid], ymn = mn[S_ + tid];
      const int xmx = mn[2*S_ + tid], ymx = mn[3*S_ + tid];
      float4 v;
      v.x = (float)xmn; v.y = (float)ymn;
      v.z = (float)(xmx - xmn); v.w = (float)(ymx - ymn);
      ((float4*)(out + O_BBOX))[b * S_ + tid] = v;
    }
  } else if (bid < NBBOX + NTEX) {
    // ---------- texture hist plane (b, c*R+r): full image, final write ----------
    const int plane = bid - NBBOX;          // b*24 + cr
    const int b = plane / (C_*R_);
    const int cr = plane - b * (C_*R_);
    int* h = (int*)smem;                    // S*TB = 10240 ints (40 KB)
    for (int i = tid; i < S_*TB_; i += 1024) h[i] = 0;
    __syncthreads();
    const int4* bp = (const int4*)(grads_bins + (size_t)plane * HW_);
    const int4* lp = (const int4*)(lab + (size_t)b * HW_);
    for (int t = tid; t < HW_/4; t += 1024) {
      const int4 bn = bp[t];
      const int4 lv = lp[t];
      atomicAdd(&h[lv.x*TB_ + bn.x], 1);
      atomicAdd(&h[lv.y*TB_ + bn.y], 1);
      atomicAdd(&h[lv.z*TB_ + bn.z], 1);
      atomicAdd(&h[lv.w*TB_ + bn.w], 1);
    }
    __syncthreads();
    // thread l: area = sum of its 10 bins (full image) -> normalize + write
    {
      const int base = tid * TB_;
      int s = 0;
      #pragma unroll
      for (int t = 0; t < TB_; ++t) s += h[base + t];
      const float inv = 1.0f / ((float)s * 24.0f + 1e-12f);
      float* o = out + O_TEX + (size_t)b * (S_ * C_*R_*TB_) + tid * (C_*R_*TB_) + cr * TB_;
      #pragma unroll
      for (int t = 0; t < TB_; ++t) o[t] = (float)h[base + t] * inv;
      if (cr == 0) out[O_AREA + b * S_ + tid] = (float)s;
    }
  } else if (bid < NHIST) {
    // ---------- color hist plane (b,c): u16-packed LDS, final write ----------
    const int plane = bid - NBBOX - NTEX;   // b*3 + c
    const int b = plane / C_;
    const int c = plane - b * C_;
    unsigned* h = smem;                     // S*CB/2 = 12800 words (51.2 KB)
    for (int i = tid; i < (S_*CB_)/2; i += 1024) h[i] = 0;
    __syncthreads();
    const int4* bp = (const int4*)(imgs_bins + (size_t)plane * HW_);
    const int4* lp = (const int4*)(lab + (size_t)b * HW_);
    for (int t = tid; t < HW_/4; t += 1024) {
      const int4 bn = bp[t];
      const int4 lv = lp[t];
      const int j0 = lv.x*CB_ + bn.x;
      const int j1 = lv.y*CB_ + bn.y;
      const int j2 = lv.z*CB_ + bn.z;
      const int j3 = lv.w*CB_ + bn.w;
      atomicAdd(&h[j0 >> 1], 1u << ((j0 & 1) << 4));
      atomicAdd(&h[j1 >> 1], 1u << ((j1 & 1) << 4));
      atomicAdd(&h[j2 >> 1], 1u << ((j2 & 1) << 4));
      atomicAdd(&h[j3 >> 1], 1u << ((j3 & 1) << 4));
    }
    __syncthreads();
    // thread l: sum 25 bins -> normalize + write (two LDS passes, no reg array)
    {
      int s = 0;
      #pragma unroll
      for (int ci = 0; ci < CB_; ++ci) {
        const int j = tid * CB_ + ci;
        s += (int)((h[j >> 1] >> ((j & 1) << 4)) & 0xFFFFu);
      }
      const float inv = 1.0f / ((float)s * 3.0f + 1e-12f);
      float* o = out + O_COLOR + (size_t)b * (S_ * C_*CB_) + tid * (C_*CB_) + c * CB_;
      #pragma unroll
      for (int ci = 0; ci < CB_; ++ci) {
        const int j = tid * CB_ + ci;
        o[ci] = (float)((h[j >> 1] >> ((j & 1) << 4)) & 0xFFFFu) * inv;
      }
    }
  } else {
    // ---------- Scharr gradients, grid-stride ----------
    const int cb = bid - NHIST;
    const int tot = B_*C_*HW_;
    for (int i = cb * 1024 + tid; i < tot; i += NCONV * 1024) {
      const int pix = i & (HW_ - 1);
      const int bc = i >> 18;
      const int x = pix & (W_ - 1);
      const int y = pix >> 9;
      const float* im = img + (size_t)bc * HW_;
      const bool xm = x > 0, xp = x < W_ - 1, ym = y > 0, yp = y < H_ - 1;
      const float i00 = (ym && xm) ? im[pix - W_ - 1] : 0.f;
      const float i01 = ym ? im[pix - W_] : 0.f;
      const float i02 = (ym && xp) ? im[pix - W_ + 1] : 0.f;
      const float i10 = xm ? im[pix - 1] : 0.f;
      const float i12 = xp ? im[pix + 1] : 0.f;
      const float i20 = (yp && xm) ? im[pix + W_ - 1] : 0.f;
      const float i21 = yp ? im[pix + W_] : 0.f;
      const float i22 = (yp && xp) ? im[pix + W_ + 1] : 0.f;
      const float gx = 3.f*(i02 - i00) + 10.f*(i12 - i10) + 3.f*(i22 - i20);
      const float gy = 3.f*(i20 - i00) + 10.f*(i21 - i01) + 3.f*(i22 - i02);
      out[O_GRADS + (size_t)(bc*2 + 0)*HW_ + pix] = gx;
      out[O_GRADS + (size_t)(bc*2 + 1)*HW_ + pix] = gy;
    }
  }
}

extern "C" void kernel_launch(void* const* d_in, const int* in_sizes, int n_in,
                              void* d_out, int out_size, void* d_ws, size_t ws_size,
                              hipStream_t stream) {
  const float* img = (const float*)d_in[0];
  const int* imgs_bins = (const int*)d_in[1];
  const int* grads_bins = (const int*)d_in[2];
  const int* reg_lab = (const int*)d_in[3];
  float* out = (float*)d_out;

  hipLaunchKernelGGL(k_fused, dim3(NGRID), dim3(1024), 0, stream,
                     img, imgs_bins, grads_bins, reg_lab, out);
}